// Round 14
// baseline (658.463 us; speedup 1.0000x reference)
//
#include <hip/hip_runtime.h>
#include <hip/hip_cooperative_groups.h>
#include <math.h>

namespace cg = cooperative_groups;

// Problem constants (fixed by reference): B=4, N=2048, D=512, H=4, LH=AH=64, T=6400,
// lengths {2048,1536,1024,1792} -> offsets {0,2048,3584,4608}, nqt {32,24,16,28}.
// hb (bf16, 768 cols): v[0:256) DEAD, q[256:512), k[512:768), head hd at +hd*64
// vtb (bf16): [d][token] V pre-transposed. Split-K: 4 key tiles/chunk, <=8 chunks.
// R14: single cooperative mega-kernel (5 phases + 4 grid.sync) — removes 4 launch gaps
// (~7-10us each, R9->R10 evidence). Grid-stride phases; occupancy-queried grid size;
// fallback to the proven 5-kernel path if cooperative launch errors.

typedef __attribute__((ext_vector_type(8))) short bf16x8;   // 8 bf16 in 4 VGPRs
typedef __attribute__((ext_vector_type(4))) float f32x4;

__device__ __forceinline__ float silu_over_2048(float v) {
    return v * __builtin_amdgcn_rcpf(2048.0f + 2048.0f * __expf(-v));
}

__device__ __forceinline__ float silu_f(float v) {
    return v * __builtin_amdgcn_rcpf(1.0f + __expf(-v));
}

__device__ __forceinline__ unsigned short f2bf(float f) {  // RNE float->bf16
    unsigned int u = __float_as_uint(f);
    u += 0x7fffu + ((u >> 16) & 1u);
    return (unsigned short)(u >> 16);
}

__device__ __forceinline__ unsigned int f2bf2(float lo, float hi) {
#if __has_builtin(__builtin_amdgcn_cvt_pk_bf16_f32)
    typedef __attribute__((ext_vector_type(2))) short bf16x2;
    bf16x2 p = __builtin_amdgcn_cvt_pk_bf16_f32(lo, hi);
    return *(unsigned int*)&p;
#else
    return (unsigned int)f2bf(lo) | ((unsigned int)f2bf(hi) << 16);
#endif
}

// =================== MEGA: all phases in one cooperative kernel ===================
__global__ __launch_bounds__(256, 4) void mega(
    const float* __restrict__ x, const float* __restrict__ uvqk,
    const float* __restrict__ ow, const float* __restrict__ ob,
    const float* __restrict__ tsw, const int* __restrict__ ts,
    const int* __restrict__ token_pos, float* __restrict__ out,
    float* __restrict__ u_out, float* __restrict__ part,
    unsigned short* __restrict__ xnb, unsigned short* __restrict__ hb,
    unsigned short* __restrict__ o_in, unsigned short* __restrict__ uvqkT,
    unsigned short* __restrict__ owb, unsigned short* __restrict__ vtb) {

    union Smem {
        struct {
            unsigned short QPs[64][72];
            unsigned short Ks[64][72];
            unsigned short Vt[64][72];
            float tqf[64], tkf[64], tw[132];
        } a;                                   // attention phase (28688 B)
        struct { unsigned short As[64][72], Bs[64][72]; } g;  // gemm phases
        float L[64][68];                       // prep phase
    };
    __shared__ Smem sm;
    __shared__ float red[8];

    cg::grid_group grid = cg::this_grid();
    const int tid = threadIdx.x;
    const int nb = gridDim.x;
    const int lane = tid & 63;
    const int w = tid >> 6;
    const int l15 = lane & 15;
    const int quad = lane >> 4;

    // ---------- Phase 1: LN (0..6399) + uvqkT transpose (6400..6527) + owb (6528..6591) ----------
    for (int bx = blockIdx.x; bx < 6592; bx += nb) {
        if (bx < 6400) {
            const float* xr = x + bx * 512;
            float a = xr[tid];
            float b = xr[tid + 256];
            float s = a + b, ss = a * a + b * b;
#pragma unroll
            for (int off = 32; off > 0; off >>= 1) {
                s += __shfl_down(s, off);
                ss += __shfl_down(ss, off);
            }
            if ((tid & 63) == 0) { red[tid >> 6] = s; red[4 + (tid >> 6)] = ss; }
            __syncthreads();
            s = red[0] + red[1] + red[2] + red[3];
            ss = red[4] + red[5] + red[6] + red[7];
            const float mean = s * (1.0f / 512.0f);
            const float var = ss * (1.0f / 512.0f) - mean * mean;  // biased (jnp.var)
            const float rstd = rsqrtf(var + 1e-6f);
            xnb[bx * 512 + tid] = f2bf((a - mean) * rstd);
            xnb[bx * 512 + tid + 256] = f2bf((b - mean) * rstd);
        } else if (bx < 6528) {
            const int t = bx - 6400;
            const int n0 = (t & 15) * 64;
            const int k0 = (t >> 4) * 64;
#pragma unroll
            for (int i = 0; i < 4; ++i) {
                const int r = (tid >> 4) + i * 16;
                const int c = (tid & 15) * 4;
                *(float4*)&sm.L[r][c] = *(const float4*)(uvqk + (k0 + r) * 1024 + n0 + c);
            }
            __syncthreads();
            const int n = tid >> 2;
            const int kb = (tid & 3) * 16;
#pragma unroll
            for (int pass = 0; pass < 2; ++pass) {
                unsigned short pk[8];
#pragma unroll
                for (int j = 0; j < 8; ++j) pk[j] = f2bf(sm.L[kb + pass * 8 + j][n]);
                *(uint4*)(uvqkT + (n0 + n) * 512 + k0 + kb + pass * 8) = *(const uint4*)pk;
            }
        } else {
            const int base = ((bx - 6528) * 256 + tid) * 8;
            float4 a = *(const float4*)(ow + base);
            float4 b = *(const float4*)(ow + base + 4);
            unsigned short pk[8] = {f2bf(a.x), f2bf(a.y), f2bf(a.z), f2bf(a.w),
                                    f2bf(b.x), f2bf(b.y), f2bf(b.z), f2bf(b.w)};
            *(uint4*)(owb + base) = *(const uint4*)pk;
        }
        __syncthreads();  // LDS/red reuse guard across grid-stride iterations
    }
    __threadfence();
    grid.sync();

    // ---------- Phase 2: h = silu(xn @ uvqk); u->fp32, q/k->hb, v->vtb (transposed) ----------
    for (int ti = blockIdx.x; ti < 1600; ti += nb) {
        const int bm = (ti >> 4) * 64;
        const int bn = (ti & 15) * 64;
        f32x4 acc[4] = {};
        for (int kc = 0; kc < 512; kc += 64) {
            __syncthreads();
#pragma unroll
            for (int i = 0; i < 2; ++i) {
                const int r = (tid >> 3) + i * 32;
                const int c = (tid & 7) * 8;
                *(uint4*)&sm.g.As[r][c] = *(const uint4*)(xnb + (bm + r) * 512 + kc + c);
                *(uint4*)&sm.g.Bs[r][c] = *(const uint4*)(uvqkT + (bn + r) * 512 + kc + c);
            }
            __syncthreads();
            const bf16x8 a0 = *(const bf16x8*)&sm.g.As[w * 16 + l15][quad * 8];
            const bf16x8 a1 = *(const bf16x8*)&sm.g.As[w * 16 + l15][32 + quad * 8];
#pragma unroll
            for (int nt = 0; nt < 4; ++nt) {
                bf16x8 b0 = *(const bf16x8*)&sm.g.Bs[nt * 16 + l15][quad * 8];
                bf16x8 b1 = *(const bf16x8*)&sm.g.Bs[nt * 16 + l15][32 + quad * 8];
                acc[nt] = __builtin_amdgcn_mfma_f32_16x16x32_bf16(a0, b0, acc[nt], 0, 0, 0);
                acc[nt] = __builtin_amdgcn_mfma_f32_16x16x32_bf16(a1, b1, acc[nt], 0, 0, 0);
            }
        }
        const int m = bm + w * 16 + quad * 4;
        if (bn < 256) {
#pragma unroll
            for (int nt = 0; nt < 4; ++nt)
#pragma unroll
                for (int reg = 0; reg < 4; ++reg)
                    u_out[(m + reg) * 256 + bn + nt * 16 + l15] = silu_f(acc[nt][reg]);
        } else if (bn < 512) {
            __syncthreads();
#pragma unroll
            for (int nt = 0; nt < 4; ++nt) {
                unsigned int p01 = f2bf2(silu_f(acc[nt][0]), silu_f(acc[nt][1]));
                unsigned int p23 = f2bf2(silu_f(acc[nt][2]), silu_f(acc[nt][3]));
                unsigned int pk2[2] = {p01, p23};
                *(uint2*)&sm.g.As[nt * 16 + l15][w * 16 + quad * 4] = *(const uint2*)pk2;
            }
            __syncthreads();
            const int sr = tid >> 3, sc = (tid & 7) * 8;
#pragma unroll
            for (int i = 0; i < 2; ++i) {
                const int r = sr + i * 32;
                *(uint4*)(vtb + (size_t)(bn - 256 + r) * 6400 + bm + sc) =
                    *(const uint4*)&sm.g.As[r][sc];
            }
        } else {
#pragma unroll
            for (int nt = 0; nt < 4; ++nt) {
                unsigned int p01 = f2bf2(silu_f(acc[nt][0]), silu_f(acc[nt][1]));
                unsigned int p23 = f2bf2(silu_f(acc[nt][2]), silu_f(acc[nt][3]));
                unsigned short* hp = hb + (size_t)m * 768 + (bn - 256) + nt * 16 + l15;
                hp[0] = (unsigned short)p01;
                hp[768] = (unsigned short)(p01 >> 16);
                hp[1536] = (unsigned short)p23;
                hp[2304] = (unsigned short)(p23 >> 16);
            }
        }
        __syncthreads();  // LDS reuse guard before next tile
    }
    __threadfence();
    grid.sync();

    // ---------- Phase 3: attention, flattened active units (1520 = 4 heads x 380) ----------
    if (tid < 129) sm.a.tw[tid] = tsw[tid];  // persists across units (barrier below)
    for (int uu = blockIdx.x; uu < 1520; uu += nb) {
        const int hd = uu & 3;
        const int unit = uu >> 2;
        int b, rem;
        if (unit < 144) { b = 0; rem = unit; }
        else if (unit < 228) { b = 1; rem = unit - 144; }
        else if (unit < 268) { b = 2; rem = unit - 228; }
        else { b = 3; rem = unit - 268; }
        // qt groups of 4 share chunk count g+1; group g starts at cum 2g(g+1)
        int g = 0;
        while (2 * (g + 1) * (g + 2) <= rem) ++g;
        const int r2 = rem - 2 * g * (g + 1);
        const int j = r2 / (g + 1);
        const int c = r2 - j * (g + 1);
        const int qt = 4 * g + j;
        const int off = (b == 0) ? 0 : (b == 1) ? 2048 : (b == 2) ? 3584 : 4608;
        const int q0 = qt * 64;
        const int kt_lo = c * 4;
        const int kt_hi = min(qt, c * 4 + 3);
        const int sr = tid >> 3;
        const int sc = (tid & 7) * 8;

        __syncthreads();  // prior unit's QPs/tw reads done before overwrite
        if (tid < 64) sm.a.tqf[tid] = (float)ts[b * 2048 + q0 + tid];
#pragma unroll
        for (int i = 0; i < 2; ++i)
            *(uint4*)&sm.a.QPs[sr + i * 32][sc] =
                *(const uint4*)(hb + (off + q0 + sr + i * 32) * 768 + 256 + hd * 64 + sc);
        __syncthreads();

        const bf16x8 aQ0 = *(const bf16x8*)&sm.a.QPs[w * 16 + l15][quad * 8];
        const bf16x8 aQ1 = *(const bf16x8*)&sm.a.QPs[w * 16 + l15][32 + quad * 8];
        const f32x4 tq4 = *(const f32x4*)&sm.a.tqf[w * 16 + quad * 4];
        const int nbase = q0 + w * 16 + quad * 4;
        f32x4 oacc[4] = {};

        for (int kt = kt_lo; kt <= kt_hi; ++kt) {
            const int m0 = kt * 64;
            __syncthreads();
#pragma unroll
            for (int i = 0; i < 2; ++i) {
                const int r = sr + i * 32;
                *(uint4*)&sm.a.Ks[r][sc] =
                    *(const uint4*)(hb + (off + m0 + r) * 768 + 512 + hd * 64 + sc);
                *(uint4*)&sm.a.Vt[r][sc] =
                    *(const uint4*)(vtb + (size_t)(hd * 64 + r) * 6400 + off + m0 + sc);
            }
            if (tid < 64) sm.a.tkf[tid] = (float)ts[b * 2048 + m0 + tid];
            __syncthreads();

            f32x4 s[4] = {};
#pragma unroll
            for (int nt = 0; nt < 4; ++nt) {
                bf16x8 b0 = *(const bf16x8*)&sm.a.Ks[nt * 16 + l15][quad * 8];
                bf16x8 b1 = *(const bf16x8*)&sm.a.Ks[nt * 16 + l15][32 + quad * 8];
                s[nt] = __builtin_amdgcn_mfma_f32_16x16x32_bf16(aQ0, b0, s[nt], 0, 0, 0);
                s[nt] = __builtin_amdgcn_mfma_f32_16x16x32_bf16(aQ1, b1, s[nt], 0, 0, 0);
            }

            const bool diag = (kt == qt);
#pragma unroll
            for (int nt = 0; nt < 4; ++nt) {
                const int m = m0 + nt * 16 + l15;
                const float tk = sm.a.tkf[nt * 16 + l15];
                float p[4];
#pragma unroll
                for (int reg = 0; reg < 4; ++reg) {
                    const float delta = fabsf(tq4[reg] - tk);
                    const int bucket = (int)(__log2f(1.0f + delta) * 0.6931471805599453f);
                    float val = s[nt][reg] + sm.a.tw[bucket];
                    float pv = silu_over_2048(val);
                    if (diag) pv = (m <= nbase + reg) ? pv : 0.0f;
                    p[reg] = pv;
                }
                const unsigned int p01 = f2bf2(p[0], p[1]);
                const unsigned int p23 = f2bf2(p[2], p[3]);
                sm.a.QPs[w * 16 + quad * 4 + 0][nt * 16 + l15] = (unsigned short)p01;
                sm.a.QPs[w * 16 + quad * 4 + 1][nt * 16 + l15] = (unsigned short)(p01 >> 16);
                sm.a.QPs[w * 16 + quad * 4 + 2][nt * 16 + l15] = (unsigned short)p23;
                sm.a.QPs[w * 16 + quad * 4 + 3][nt * 16 + l15] = (unsigned short)(p23 >> 16);
            }
            // wave reads back only its own Ps rows -> intra-wave ordering suffices

            const bf16x8 aP0 = *(const bf16x8*)&sm.a.QPs[w * 16 + l15][quad * 8];
            const bf16x8 aP1 = *(const bf16x8*)&sm.a.QPs[w * 16 + l15][32 + quad * 8];
#pragma unroll
            for (int nt = 0; nt < 4; ++nt) {
                bf16x8 v0 = *(const bf16x8*)&sm.a.Vt[nt * 16 + l15][quad * 8];
                bf16x8 v1 = *(const bf16x8*)&sm.a.Vt[nt * 16 + l15][32 + quad * 8];
                oacc[nt] = __builtin_amdgcn_mfma_f32_16x16x32_bf16(aP0, v0, oacc[nt], 0, 0, 0);
                oacc[nt] = __builtin_amdgcn_mfma_f32_16x16x32_bf16(aP1, v1, oacc[nt], 0, 0, 0);
            }
        }

        float* pc = part + (size_t)c * (6400 * 256);
#pragma unroll
        for (int nt = 0; nt < 4; ++nt)
#pragma unroll
            for (int reg = 0; reg < 4; ++reg)
                pc[(off + q0 + w * 16 + quad * 4 + reg) * 256 + hd * 64 + nt * 16 + l15] =
                    oacc[nt][reg];
    }
    __threadfence();
    grid.sync();

    // ---------- Phase 4: o_in = bf16(u * LN(sum_c part)) ----------
    for (int row = blockIdx.x; row < 6400; row += nb) {
        const int qt = token_pos[row] >> 6;
        const int nch = (qt + 4) >> 2;
        float a = 0.0f;
        for (int c = 0; c < nch; ++c) a += part[(size_t)c * (6400 * 256) + row * 256 + tid];
        float s = a, ss = a * a;
#pragma unroll
        for (int off = 32; off > 0; off >>= 1) {
            s += __shfl_down(s, off);
            ss += __shfl_down(ss, off);
        }
        if ((tid & 63) == 0) { red[tid >> 6] = s; red[4 + (tid >> 6)] = ss; }
        __syncthreads();
        s = red[0] + red[1] + red[2] + red[3];
        ss = red[4] + red[5] + red[6] + red[7];
        const float mean = s * (1.0f / 256.0f);
        const float var = ss * (1.0f / 256.0f) - mean * mean;
        const float rstd = rsqrtf(var + 1e-6f);
        o_in[row * 256 + tid] = f2bf(u_out[row * 256 + tid] * (a - mean) * rstd);
        __syncthreads();  // red reuse guard
    }
    __threadfence();
    grid.sync();

    // ---------- Phase 5: out = o_in @ ow^T + ob + x ----------
    for (int ti = blockIdx.x; ti < 800; ti += nb) {
        const int bm = (ti >> 3) * 64;
        const int bn = (ti & 7) * 64;
        f32x4 acc[4] = {};
        for (int kc = 0; kc < 256; kc += 64) {
            __syncthreads();
#pragma unroll
            for (int i = 0; i < 2; ++i) {
                const int r = (tid >> 3) + i * 32;
                const int c = (tid & 7) * 8;
                *(uint4*)&sm.g.As[r][c] = *(const uint4*)(o_in + (bm + r) * 256 + kc + c);
                *(uint4*)&sm.g.Bs[r][c] = *(const uint4*)(owb + (bn + r) * 256 + kc + c);
            }
            __syncthreads();
            const bf16x8 a0 = *(const bf16x8*)&sm.g.As[w * 16 + l15][quad * 8];
            const bf16x8 a1 = *(const bf16x8*)&sm.g.As[w * 16 + l15][32 + quad * 8];
#pragma unroll
            for (int nt = 0; nt < 4; ++nt) {
                bf16x8 b0 = *(const bf16x8*)&sm.g.Bs[nt * 16 + l15][quad * 8];
                bf16x8 b1 = *(const bf16x8*)&sm.g.Bs[nt * 16 + l15][32 + quad * 8];
                acc[nt] = __builtin_amdgcn_mfma_f32_16x16x32_bf16(a0, b0, acc[nt], 0, 0, 0);
                acc[nt] = __builtin_amdgcn_mfma_f32_16x16x32_bf16(a1, b1, acc[nt], 0, 0, 0);
            }
        }
        const int m = bm + w * 16 + quad * 4;
#pragma unroll
        for (int nt = 0; nt < 4; ++nt) {
            const int d = bn + nt * 16 + l15;
            const float bias = ob[d];
#pragma unroll
            for (int reg = 0; reg < 4; ++reg)
                out[(m + reg) * 512 + d] = acc[nt][reg] + bias + x[(m + reg) * 512 + d];
        }
        __syncthreads();
    }
}

// =================== Fallback path: proven R13 5-kernel pipeline ===================
__global__ __launch_bounds__(256) void k1_ln_prep(const float* __restrict__ x,
                                                  unsigned short* __restrict__ xnb,
                                                  const float* __restrict__ uvqk,
                                                  unsigned short* __restrict__ uvqkT,
                                                  const float* __restrict__ ow,
                                                  unsigned short* __restrict__ owb) {
    __shared__ float L[64][68];
    const int tid = threadIdx.x;
    const int bx = blockIdx.x;
    if (bx < 6400) {
        const float* xr = x + bx * 512;
        float a = xr[tid];
        float b = xr[tid + 256];
        float s = a + b, ss = a * a + b * b;
#pragma unroll
        for (int off = 32; off > 0; off >>= 1) {
            s += __shfl_down(s, off);
            ss += __shfl_down(ss, off);
        }
        float* red = &L[0][0];
        if ((tid & 63) == 0) { red[tid >> 6] = s; red[4 + (tid >> 6)] = ss; }
        __syncthreads();
        s = red[0] + red[1] + red[2] + red[3];
        ss = red[4] + red[5] + red[6] + red[7];
        const float mean = s * (1.0f / 512.0f);
        const float var = ss * (1.0f / 512.0f) - mean * mean;
        const float rstd = rsqrtf(var + 1e-6f);
        xnb[bx * 512 + tid] = f2bf((a - mean) * rstd);
        xnb[bx * 512 + tid + 256] = f2bf((b - mean) * rstd);
    } else if (bx < 6528) {
        const int t = bx - 6400;
        const int n0 = (t & 15) * 64;
        const int k0 = (t >> 4) * 64;
#pragma unroll
        for (int i = 0; i < 4; ++i) {
            const int r = (tid >> 4) + i * 16;
            const int c = (tid & 15) * 4;
            *(float4*)&L[r][c] = *(const float4*)(uvqk + (k0 + r) * 1024 + n0 + c);
        }
        __syncthreads();
        const int n = tid >> 2;
        const int kb = (tid & 3) * 16;
#pragma unroll
        for (int pass = 0; pass < 2; ++pass) {
            unsigned short pk[8];
#pragma unroll
            for (int j = 0; j < 8; ++j) pk[j] = f2bf(L[kb + pass * 8 + j][n]);
            *(uint4*)(uvqkT + (n0 + n) * 512 + k0 + kb + pass * 8) = *(const uint4*)pk;
        }
    } else {
        const int base = ((bx - 6528) * 256 + tid) * 8;
        float4 a = *(const float4*)(ow + base);
        float4 b = *(const float4*)(ow + base + 4);
        unsigned short pk[8] = {f2bf(a.x), f2bf(a.y), f2bf(a.z), f2bf(a.w),
                                f2bf(b.x), f2bf(b.y), f2bf(b.z), f2bf(b.w)};
        *(uint4*)(owb + base) = *(const uint4*)pk;
    }
}

__global__ __launch_bounds__(256, 4) void k2_gemm1(const unsigned short* __restrict__ A,
                                                   const unsigned short* __restrict__ Bt,
                                                   float* __restrict__ u_out,
                                                   unsigned short* __restrict__ hb,
                                                   unsigned short* __restrict__ vtb) {
    __shared__ __align__(16) unsigned short As[64][72];
    __shared__ __align__(16) unsigned short Bs[64][72];
    const int tid = threadIdx.x;
    const int lane = tid & 63;
    const int w = tid >> 6;
    const int l15 = lane & 15;
    const int quad = lane >> 4;
    const int bm = blockIdx.y * 64;
    const int bn = blockIdx.x * 64;

    f32x4 acc[4] = {};
    for (int kc = 0; kc < 512; kc += 64) {
        __syncthreads();
#pragma unroll
        for (int i = 0; i < 2; ++i) {
            const int r = (tid >> 3) + i * 32;
            const int c = (tid & 7) * 8;
            *(uint4*)&As[r][c] = *(const uint4*)(A + (bm + r) * 512 + kc + c);
            *(uint4*)&Bs[r][c] = *(const uint4*)(Bt + (bn + r) * 512 + kc + c);
        }
        __syncthreads();
        const bf16x8 a0 = *(const bf16x8*)&As[w * 16 + l15][quad * 8];
        const bf16x8 a1 = *(const bf16x8*)&As[w * 16 + l15][32 + quad * 8];
#pragma unroll
        for (int nt = 0; nt < 4; ++nt) {
            bf16x8 b0 = *(const bf16x8*)&Bs[nt * 16 + l15][quad * 8];
            bf16x8 b1 = *(const bf16x8*)&Bs[nt * 16 + l15][32 + quad * 8];
            acc[nt] = __builtin_amdgcn_mfma_f32_16x16x32_bf16(a0, b0, acc[nt], 0, 0, 0);
            acc[nt] = __builtin_amdgcn_mfma_f32_16x16x32_bf16(a1, b1, acc[nt], 0, 0, 0);
        }
    }
    const int m = bm + w * 16 + quad * 4;
    if (bn < 256) {
#pragma unroll
        for (int nt = 0; nt < 4; ++nt)
#pragma unroll
            for (int reg = 0; reg < 4; ++reg)
                u_out[(m + reg) * 256 + bn + nt * 16 + l15] = silu_f(acc[nt][reg]);
    } else if (bn < 512) {
        __syncthreads();
#pragma unroll
        for (int nt = 0; nt < 4; ++nt) {
            unsigned int p01 = f2bf2(silu_f(acc[nt][0]), silu_f(acc[nt][1]));
            unsigned int p23 = f2bf2(silu_f(acc[nt][2]), silu_f(acc[nt][3]));
            unsigned int pk2[2] = {p01, p23};
            *(uint2*)&As[nt * 16 + l15][w * 16 + quad * 4] = *(const uint2*)pk2;
        }
        __syncthreads();
        const int sr = tid >> 3, sc = (tid & 7) * 8;
#pragma unroll
        for (int i = 0; i < 2; ++i) {
            const int r = sr + i * 32;
            *(uint4*)(vtb + (size_t)(bn - 256 + r) * 6400 + bm + sc) =
                *(const uint4*)&As[r][sc];
        }
    } else {
#pragma unroll
        for (int nt = 0; nt < 4; ++nt) {
            unsigned int p01 = f2bf2(silu_f(acc[nt][0]), silu_f(acc[nt][1]));
            unsigned int p23 = f2bf2(silu_f(acc[nt][2]), silu_f(acc[nt][3]));
            unsigned short* hp = hb + (size_t)m * 768 + (bn - 256) + nt * 16 + l15;
            hp[0] = (unsigned short)p01;
            hp[768] = (unsigned short)(p01 >> 16);
            hp[1536] = (unsigned short)p23;
            hp[2304] = (unsigned short)(p23 >> 16);
        }
    }
}

__global__ __launch_bounds__(256, 5) void k3_attn(const unsigned short* __restrict__ hb,
                                                  const unsigned short* __restrict__ vtb,
                                                  const int* __restrict__ ts,
                                                  const float* __restrict__ tsw,
                                                  const int* __restrict__ offs,
                                                  float* __restrict__ part) {
    const int qt = 31 - (blockIdx.x & 31);
    const int c = blockIdx.x >> 5;
    const int b = blockIdx.y;
    const int hd = blockIdx.z;
    const int off = offs[b];
    const int len = offs[b + 1] - off;
    const int nqt = len >> 6;
    if (qt >= nqt || c * 4 > qt) return;
    const int q0 = qt * 64;
    const int kt_lo = c * 4;
    const int kt_hi = min(qt, c * 4 + 3);

    __shared__ __align__(16) unsigned short QPs[64][72];
    __shared__ __align__(16) unsigned short Ks[64][72];
    __shared__ __align__(16) unsigned short Vt[64][72];
    __shared__ float tqf[64], tkf[64];
    __shared__ float tw[132];

    const int tid = threadIdx.x;
    const int lane = tid & 63;
    const int w = tid >> 6;
    const int l15 = lane & 15;
    const int quad = lane >> 4;
    const int sr = tid >> 3;
    const int sc = (tid & 7) * 8;

    if (tid < 129) tw[tid] = tsw[tid];
    if (tid < 64) tqf[tid] = (float)ts[b * 2048 + q0 + tid];
#pragma unroll
    for (int i = 0; i < 2; ++i)
        *(uint4*)&QPs[sr + i * 32][sc] =
            *(const uint4*)(hb + (off + q0 + sr + i * 32) * 768 + 256 + hd * 64 + sc);
    __syncthreads();

    const bf16x8 aQ0 = *(const bf16x8*)&QPs[w * 16 + l15][quad * 8];
    const bf16x8 aQ1 = *(const bf16x8*)&QPs[w * 16 + l15][32 + quad * 8];
    const f32x4 tq4 = *(const f32x4*)&tqf[w * 16 + quad * 4];
    const int nbase = q0 + w * 16 + quad * 4;

    f32x4 oacc[4] = {};

    for (int kt = kt_lo; kt <= kt_hi; ++kt) {
        const int m0 = kt * 64;
        __syncthreads();
#pragma unroll
        for (int i = 0; i < 2; ++i) {
            const int r = sr + i * 32;
            *(uint4*)&Ks[r][sc] =
                *(const uint4*)(hb + (off + m0 + r) * 768 + 512 + hd * 64 + sc);
            *(uint4*)&Vt[r][sc] =
                *(const uint4*)(vtb + (size_t)(hd * 64 + r) * 6400 + off + m0 + sc);
        }
        if (tid < 64) tkf[tid] = (float)ts[b * 2048 + m0 + tid];
        __syncthreads();

        f32x4 s[4] = {};
#pragma unroll
        for (int nt = 0; nt < 4; ++nt) {
            bf16x8 b0 = *(const bf16x8*)&Ks[nt * 16 + l15][quad * 8];
            bf16x8 b1 = *(const bf16x8*)&Ks[nt * 16 + l15][32 + quad * 8];
            s[nt] = __builtin_amdgcn_mfma_f32_16x16x32_bf16(aQ0, b0, s[nt], 0, 0, 0);
            s[nt] = __builtin_amdgcn_mfma_f32_16x16x32_bf16(aQ1, b1, s[nt], 0, 0, 0);
        }

        const bool diag = (kt == qt);
#pragma unroll
        for (int nt = 0; nt < 4; ++nt) {
            const int m = m0 + nt * 16 + l15;
            const float tk = tkf[nt * 16 + l15];
            float p[4];
#pragma unroll
            for (int reg = 0; reg < 4; ++reg) {
                const float delta = fabsf(tq4[reg] - tk);
                const int bucket = (int)(__log2f(1.0f + delta) * 0.6931471805599453f);
                float val = s[nt][reg] + tw[bucket];
                float pv = silu_over_2048(val);
                if (diag) pv = (m <= nbase + reg) ? pv : 0.0f;
                p[reg] = pv;
            }
            const unsigned int p01 = f2bf2(p[0], p[1]);
            const unsigned int p23 = f2bf2(p[2], p[3]);
            QPs[w * 16 + quad * 4 + 0][nt * 16 + l15] = (unsigned short)p01;
            QPs[w * 16 + quad * 4 + 1][nt * 16 + l15] = (unsigned short)(p01 >> 16);
            QPs[w * 16 + quad * 4 + 2][nt * 16 + l15] = (unsigned short)p23;
            QPs[w * 16 + quad * 4 + 3][nt * 16 + l15] = (unsigned short)(p23 >> 16);
        }

        const bf16x8 aP0 = *(const bf16x8*)&QPs[w * 16 + l15][quad * 8];
        const bf16x8 aP1 = *(const bf16x8*)&QPs[w * 16 + l15][32 + quad * 8];
#pragma unroll
        for (int nt = 0; nt < 4; ++nt) {
            bf16x8 v0 = *(const bf16x8*)&Vt[nt * 16 + l15][quad * 8];
            bf16x8 v1 = *(const bf16x8*)&Vt[nt * 16 + l15][32 + quad * 8];
            oacc[nt] = __builtin_amdgcn_mfma_f32_16x16x32_bf16(aP0, v0, oacc[nt], 0, 0, 0);
            oacc[nt] = __builtin_amdgcn_mfma_f32_16x16x32_bf16(aP1, v1, oacc[nt], 0, 0, 0);
        }
    }

    float* pc = part + (size_t)c * (6400 * 256);
#pragma unroll
    for (int nt = 0; nt < 4; ++nt)
#pragma unroll
        for (int reg = 0; reg < 4; ++reg)
            pc[(off + q0 + w * 16 + quad * 4 + reg) * 256 + hd * 64 + nt * 16 + l15] =
                oacc[nt][reg];
}

__global__ __launch_bounds__(256) void k4a_ln(const float* __restrict__ part,
                                              const float* __restrict__ u_in,
                                              const int* __restrict__ token_pos,
                                              unsigned short* __restrict__ o_in) {
    const int row = blockIdx.x;
    const int tid = threadIdx.x;
    const int qt = token_pos[row] >> 6;
    const int nch = (qt + 4) >> 2;
    float a = 0.0f;
    for (int c = 0; c < nch; ++c) a += part[(size_t)c * (6400 * 256) + row * 256 + tid];
    float s = a, ss = a * a;
#pragma unroll
    for (int off = 32; off > 0; off >>= 1) {
        s += __shfl_down(s, off);
        ss += __shfl_down(ss, off);
    }
    __shared__ float red[8];
    if ((tid & 63) == 0) { red[tid >> 6] = s; red[4 + (tid >> 6)] = ss; }
    __syncthreads();
    s = red[0] + red[1] + red[2] + red[3];
    ss = red[4] + red[5] + red[6] + red[7];
    const float mean = s * (1.0f / 256.0f);
    const float var = ss * (1.0f / 256.0f) - mean * mean;
    const float rstd = rsqrtf(var + 1e-6f);
    o_in[row * 256 + tid] = f2bf(u_in[row * 256 + tid] * (a - mean) * rstd);
}

__global__ __launch_bounds__(256, 4) void k4b_gemm2(const unsigned short* __restrict__ A,
                                                    const unsigned short* __restrict__ owb,
                                                    const float* __restrict__ ob,
                                                    const float* __restrict__ x,
                                                    float* __restrict__ out) {
    __shared__ __align__(16) unsigned short As[64][72];
    __shared__ __align__(16) unsigned short Bs[64][72];
    const int tid = threadIdx.x;
    const int lane = tid & 63;
    const int w = tid >> 6;
    const int l15 = lane & 15;
    const int quad = lane >> 4;
    const int bm = blockIdx.y * 64;
    const int bn = blockIdx.x * 64;

    f32x4 acc[4] = {};
    for (int kc = 0; kc < 256; kc += 64) {
        __syncthreads();
#pragma unroll
        for (int i = 0; i < 2; ++i) {
            const int r = (tid >> 3) + i * 32;
            const int c = (tid & 7) * 8;
            *(uint4*)&As[r][c] = *(const uint4*)(A + (bm + r) * 256 + kc + c);
            *(uint4*)&Bs[r][c] = *(const uint4*)(owb + (bn + r) * 256 + kc + c);
        }
        __syncthreads();
        const bf16x8 a0 = *(const bf16x8*)&As[w * 16 + l15][quad * 8];
        const bf16x8 a1 = *(const bf16x8*)&As[w * 16 + l15][32 + quad * 8];
#pragma unroll
        for (int nt = 0; nt < 4; ++nt) {
            bf16x8 b0 = *(const bf16x8*)&Bs[nt * 16 + l15][quad * 8];
            bf16x8 b1 = *(const bf16x8*)&Bs[nt * 16 + l15][32 + quad * 8];
            acc[nt] = __builtin_amdgcn_mfma_f32_16x16x32_bf16(a0, b0, acc[nt], 0, 0, 0);
            acc[nt] = __builtin_amdgcn_mfma_f32_16x16x32_bf16(a1, b1, acc[nt], 0, 0, 0);
        }
    }
    const int m = bm + w * 16 + quad * 4;
#pragma unroll
    for (int nt = 0; nt < 4; ++nt) {
        const int d = bn + nt * 16 + l15;
        const float bias = ob[d];
#pragma unroll
        for (int reg = 0; reg < 4; ++reg)
            out[(m + reg) * 512 + d] = acc[nt][reg] + bias + x[(m + reg) * 512 + d];
    }
}

extern "C" void kernel_launch(void* const* d_in, const int* in_sizes, int n_in,
                              void* d_out, int out_size, void* d_ws, size_t ws_size,
                              hipStream_t stream) {
    const float* x = (const float*)d_in[0];       // [6400,512]
    const float* uvqk = (const float*)d_in[1];    // [512,1024]
    const float* ow = (const float*)d_in[2];      // [512,256]
    const float* ob = (const float*)d_in[3];      // [512]
    const float* tsw = (const float*)d_in[4];     // [129]
    const int* ts = (const int*)d_in[5];          // [4,2048]
    const int* offs = (const int*)d_in[7];        // [5]
    const int* token_pos = (const int*)d_in[9];   // [6400]
    float* out = (float*)d_out;                   // [6400,512]

    float* ws = (float*)d_ws;
    float* u = ws;                                // 6400*256 f32
    float* part = u + 6400 * 256;                 // 8*6400*256 f32
    unsigned short* xnb = (unsigned short*)(part + 8 * 6400 * 256);  // 6400*512 bf16
    unsigned short* hb = xnb + 6400 * 512;        // 6400*768 bf16
    unsigned short* o_in = hb + 6400 * 768;       // 6400*256 bf16
    unsigned short* uvqkT = o_in + 6400 * 256;    // 1024*512 bf16
    unsigned short* owb = uvqkT + 1024 * 512;     // 512*256 bf16
    unsigned short* vtb = owb + 512 * 256;        // 256*6400 bf16

    // grid size: co-residency-safe (query occupancy, clamp to 1024 = 4/CU target)
    int maxB = 0;
    hipError_t qerr = hipOccupancyMaxActiveBlocksPerMultiprocessor(&maxB, (const void*)mega, 256, 0);
    int nblocks = (qerr == hipSuccess && maxB > 0) ? maxB * 256 : 0;
    if (nblocks > 1024) nblocks = 1024;

    hipError_t lerr = hipErrorUnknown;
    if (nblocks >= 256) {
        void* args[] = {(void*)&x, (void*)&uvqk, (void*)&ow, (void*)&ob, (void*)&tsw,
                        (void*)&ts, (void*)&token_pos, (void*)&out, (void*)&u, (void*)&part,
                        (void*)&xnb, (void*)&hb, (void*)&o_in, (void*)&uvqkT, (void*)&owb,
                        (void*)&vtb};
        lerr = hipLaunchCooperativeKernel((const void*)mega, dim3(nblocks), dim3(256), args, 0,
                                          stream);
    }
    if (lerr != hipSuccess) {
        // fallback: proven 5-kernel path (deterministic — same branch every call)
        k1_ln_prep<<<6592, 256, 0, stream>>>(x, xnb, uvqk, uvqkT, ow, owb);
        k2_gemm1<<<dim3(16, 100), 256, 0, stream>>>(xnb, uvqkT, u, hb, vtb);
        k3_attn<<<dim3(256, 4, 4), 256, 0, stream>>>(hb, vtb, ts, tsw, offs, part);
        k4a_ln<<<6400, 256, 0, stream>>>(part, u, token_pos, o_in);
        k4b_gemm2<<<dim3(8, 100), 256, 0, stream>>>(o_in, owb, ob, x, out);
    }
}

// Round 15
// 160.207 us; speedup vs baseline: 4.1101x; 4.1101x over previous
//
#include <hip/hip_runtime.h>
#include <math.h>

// Problem constants (fixed by reference):
// B=4, N=2048, D=512, H=4, LH=AH=64, T=6400, lengths {2048,1536,1024,1792} (all %64==0)
// hb (bf16, 768 cols): v[0:256) DEAD/unwritten, q[256:512), k[512:768), head hd at +hd*64
// vtb (bf16): [d][token] V pre-transposed, written by k2's epilogue
// K3 split-K: 4 key tiles per chunk, max 8 chunks (qt<=31), LPT order, Qs/Ps alias, (256,5).
// 5-kernel graph = the proven skeleton (R11 fusion / R12 occupancy push / R14 cooperative
// mega all regressed: VGPR cliffs, spills, and grid.sync spin across non-coherent XCDs).
// R15: k1 LN -> one wave per row (4 rows/block, no block barriers, 6400->1600 blocks).

typedef __attribute__((ext_vector_type(8))) short bf16x8;   // 8 bf16 in 4 VGPRs
typedef __attribute__((ext_vector_type(4))) float f32x4;

__device__ __forceinline__ float silu_over_2048(float v) {
    return v * __builtin_amdgcn_rcpf(2048.0f + 2048.0f * __expf(-v));
}

__device__ __forceinline__ float silu_f(float v) {
    return v * __builtin_amdgcn_rcpf(1.0f + __expf(-v));
}

__device__ __forceinline__ unsigned short f2bf(float f) {  // RNE float->bf16
    unsigned int u = __float_as_uint(f);
    u += 0x7fffu + ((u >> 16) & 1u);
    return (unsigned short)(u >> 16);
}

__device__ __forceinline__ unsigned int f2bf2(float lo, float hi) {
#if __has_builtin(__builtin_amdgcn_cvt_pk_bf16_f32)
    typedef __attribute__((ext_vector_type(2))) short bf16x2;
    bf16x2 p = __builtin_amdgcn_cvt_pk_bf16_f32(lo, hi);
    return *(unsigned int*)&p;
#else
    return (unsigned int)f2bf(lo) | ((unsigned int)f2bf(hi) << 16);
#endif
}

// ---------------- K1: LN one-wave-per-row (blocks 0..1599, 4 rows each) +
//                  uvqkT transpose (1600..1727) + owb cast (1728..1791) ----------------
__global__ __launch_bounds__(256) void k1_ln_prep(const float* __restrict__ x,
                                                  unsigned short* __restrict__ xnb,
                                                  const float* __restrict__ uvqk,
                                                  unsigned short* __restrict__ uvqkT,
                                                  const float* __restrict__ ow,
                                                  unsigned short* __restrict__ owb) {
    const int tid = threadIdx.x;
    const int bx = blockIdx.x;
    if (bx < 1600) {
        // one wave per row: lane handles 8 contiguous floats; wave-shuffle reduction only
        const int row = bx * 4 + (tid >> 6);
        const int lane = tid & 63;
        const float* xr = x + row * 512 + lane * 8;
        const float4 v0 = *(const float4*)xr;
        const float4 v1 = *(const float4*)(xr + 4);
        float s = v0.x + v0.y + v0.z + v0.w + v1.x + v1.y + v1.z + v1.w;
        float ss = v0.x * v0.x + v0.y * v0.y + v0.z * v0.z + v0.w * v0.w +
                   v1.x * v1.x + v1.y * v1.y + v1.z * v1.z + v1.w * v1.w;
#pragma unroll
        for (int off = 32; off > 0; off >>= 1) {
            s += __shfl_down(s, off);
            ss += __shfl_down(ss, off);
        }
        s = __shfl(s, 0);
        ss = __shfl(ss, 0);
        const float mean = s * (1.0f / 512.0f);
        const float var = ss * (1.0f / 512.0f) - mean * mean;  // biased, matches jnp.var
        const float rstd = rsqrtf(var + 1e-6f);
        unsigned int pk[4];
        pk[0] = f2bf2((v0.x - mean) * rstd, (v0.y - mean) * rstd);
        pk[1] = f2bf2((v0.z - mean) * rstd, (v0.w - mean) * rstd);
        pk[2] = f2bf2((v1.x - mean) * rstd, (v1.y - mean) * rstd);
        pk[3] = f2bf2((v1.z - mean) * rstd, (v1.w - mean) * rstd);
        *(uint4*)(xnb + row * 512 + lane * 8) = *(const uint4*)pk;
    } else if (bx < 1728) {
        __shared__ float L[64][68];
        const int t = bx - 1600;
        const int n0 = (t & 15) * 64;
        const int k0 = (t >> 4) * 64;
#pragma unroll
        for (int i = 0; i < 4; ++i) {
            const int r = (tid >> 4) + i * 16;
            const int c = (tid & 15) * 4;
            *(float4*)&L[r][c] = *(const float4*)(uvqk + (k0 + r) * 1024 + n0 + c);
        }
        __syncthreads();
        const int n = tid >> 2;
        const int kb = (tid & 3) * 16;
#pragma unroll
        for (int pass = 0; pass < 2; ++pass) {
            unsigned short pk[8];
#pragma unroll
            for (int j = 0; j < 8; ++j) pk[j] = f2bf(L[kb + pass * 8 + j][n]);
            *(uint4*)(uvqkT + (n0 + n) * 512 + k0 + kb + pass * 8) = *(const uint4*)pk;
        }
    } else {
        const int base = ((bx - 1728) * 256 + tid) * 8;
        float4 a = *(const float4*)(ow + base);
        float4 b = *(const float4*)(ow + base + 4);
        unsigned short pk[8] = {f2bf(a.x), f2bf(a.y), f2bf(a.z), f2bf(a.w),
                                f2bf(b.x), f2bf(b.y), f2bf(b.z), f2bf(b.w)};
        *(uint4*)(owb + base) = *(const uint4*)pk;
    }
}

// ---------------- K2: h = silu(xn @ uvqk); u -> fp32, q/k -> hb bf16, v -> vtb bf16 (transposed) ----------------
__global__ __launch_bounds__(256, 4) void k2_gemm1(const unsigned short* __restrict__ A,
                                                   const unsigned short* __restrict__ Bt,
                                                   float* __restrict__ u_out,
                                                   unsigned short* __restrict__ hb,
                                                   unsigned short* __restrict__ vtb) {
    __shared__ __align__(16) unsigned short As[64][72];
    __shared__ __align__(16) unsigned short Bs[64][72];  // [n][k]
    const int tid = threadIdx.x;
    const int lane = tid & 63;
    const int w = tid >> 6;
    const int l15 = lane & 15;
    const int quad = lane >> 4;
    const int bm = blockIdx.y * 64;
    const int bn = blockIdx.x * 64;

    f32x4 acc[4] = {};
    for (int kc = 0; kc < 512; kc += 64) {
        __syncthreads();
#pragma unroll
        for (int i = 0; i < 2; ++i) {
            const int r = (tid >> 3) + i * 32;
            const int c = (tid & 7) * 8;
            *(uint4*)&As[r][c] = *(const uint4*)(A + (bm + r) * 512 + kc + c);
            *(uint4*)&Bs[r][c] = *(const uint4*)(Bt + (bn + r) * 512 + kc + c);
        }
        __syncthreads();
        const bf16x8 a0 = *(const bf16x8*)&As[w * 16 + l15][quad * 8];
        const bf16x8 a1 = *(const bf16x8*)&As[w * 16 + l15][32 + quad * 8];
#pragma unroll
        for (int nt = 0; nt < 4; ++nt) {
            bf16x8 b0 = *(const bf16x8*)&Bs[nt * 16 + l15][quad * 8];
            bf16x8 b1 = *(const bf16x8*)&Bs[nt * 16 + l15][32 + quad * 8];
            acc[nt] = __builtin_amdgcn_mfma_f32_16x16x32_bf16(a0, b0, acc[nt], 0, 0, 0);
            acc[nt] = __builtin_amdgcn_mfma_f32_16x16x32_bf16(a1, b1, acc[nt], 0, 0, 0);
        }
    }
    const int m = bm + w * 16 + quad * 4;
    if (bn < 256) {  // u region -> fp32
#pragma unroll
        for (int nt = 0; nt < 4; ++nt)
#pragma unroll
            for (int reg = 0; reg < 4; ++reg)
                u_out[(m + reg) * 256 + bn + nt * 16 + l15] = silu_f(acc[nt][reg]);
    } else if (bn < 512) {  // v region -> vtb (transposed) only
        __syncthreads();  // all waves done with As before reuse
#pragma unroll
        for (int nt = 0; nt < 4; ++nt) {
            unsigned int p01 = f2bf2(silu_f(acc[nt][0]), silu_f(acc[nt][1]));
            unsigned int p23 = f2bf2(silu_f(acc[nt][2]), silu_f(acc[nt][3]));
            unsigned int pk2[2] = {p01, p23};
            *(uint2*)&As[nt * 16 + l15][w * 16 + quad * 4] = *(const uint2*)pk2;
        }
        __syncthreads();
        const int sr = tid >> 3, sc = (tid & 7) * 8;
#pragma unroll
        for (int i = 0; i < 2; ++i) {
            const int r = sr + i * 32;
            *(uint4*)(vtb + (size_t)(bn - 256 + r) * 6400 + bm + sc) =
                *(const uint4*)&As[r][sc];
        }
    } else {  // q/k region -> hb (packed convert, scalar scatter stores)
#pragma unroll
        for (int nt = 0; nt < 4; ++nt) {
            unsigned int p01 = f2bf2(silu_f(acc[nt][0]), silu_f(acc[nt][1]));
            unsigned int p23 = f2bf2(silu_f(acc[nt][2]), silu_f(acc[nt][3]));
            unsigned short* hp = hb + (size_t)m * 768 + (bn - 256) + nt * 16 + l15;
            hp[0] = (unsigned short)p01;
            hp[768] = (unsigned short)(p01 >> 16);
            hp[1536] = (unsigned short)p23;
            hp[2304] = (unsigned short)(p23 >> 16);
        }
    }
}

// ---------------- K3: fused jagged SiLU attention, split-K (chunk=4), LPT order ----------------
__global__ __launch_bounds__(256, 5) void k3_attn(const unsigned short* __restrict__ hb,
                                                  const unsigned short* __restrict__ vtb,
                                                  const int* __restrict__ ts,
                                                  const float* __restrict__ tsw,
                                                  const int* __restrict__ offs,
                                                  float* __restrict__ part) {
    const int qt = 31 - (blockIdx.x & 31);  // LPT: longest blocks dispatch first
    const int c = blockIdx.x >> 5;
    const int b = blockIdx.y;
    const int hd = blockIdx.z;
    const int off = offs[b];
    const int len = offs[b + 1] - off;
    const int nqt = len >> 6;
    if (qt >= nqt || c * 4 > qt) return;
    const int q0 = qt * 64;
    const int kt_lo = c * 4;
    const int kt_hi = min(qt, c * 4 + 3);

    __shared__ __align__(16) unsigned short QPs[64][72];  // Qs during init, Ps in loop
    __shared__ __align__(16) unsigned short Ks[64][72];
    __shared__ __align__(16) unsigned short Vt[64][72];   // [lh][key]
    __shared__ float tqf[64], tkf[64];
    __shared__ float tw[132];

    const int tid = threadIdx.x;
    const int lane = tid & 63;
    const int w = tid >> 6;
    const int l15 = lane & 15;
    const int quad = lane >> 4;
    const int sr = tid >> 3;
    const int sc = (tid & 7) * 8;

    if (tid < 129) tw[tid] = tsw[tid];
    if (tid < 64) tqf[tid] = (float)ts[b * 2048 + q0 + tid];
#pragma unroll
    for (int i = 0; i < 2; ++i)
        *(uint4*)&QPs[sr + i * 32][sc] =
            *(const uint4*)(hb + (off + q0 + sr + i * 32) * 768 + 256 + hd * 64 + sc);
    __syncthreads();

    const bf16x8 aQ0 = *(const bf16x8*)&QPs[w * 16 + l15][quad * 8];
    const bf16x8 aQ1 = *(const bf16x8*)&QPs[w * 16 + l15][32 + quad * 8];
    const f32x4 tq4 = *(const f32x4*)&tqf[w * 16 + quad * 4];
    const int nbase = q0 + w * 16 + quad * 4;

    f32x4 oacc[4] = {};

    for (int kt = kt_lo; kt <= kt_hi; ++kt) {
        const int m0 = kt * 64;
        __syncthreads();  // prior iteration's Ks/Vt/Ps reads done
#pragma unroll
        for (int i = 0; i < 2; ++i) {
            const int r = sr + i * 32;
            *(uint4*)&Ks[r][sc] =
                *(const uint4*)(hb + (off + m0 + r) * 768 + 512 + hd * 64 + sc);
            *(uint4*)&Vt[r][sc] =
                *(const uint4*)(vtb + (size_t)(hd * 64 + r) * 6400 + off + m0 + sc);
        }
        if (tid < 64) tkf[tid] = (float)ts[b * 2048 + m0 + tid];
        __syncthreads();

        // S = Q @ K^T
        f32x4 s[4] = {};
#pragma unroll
        for (int nt = 0; nt < 4; ++nt) {
            bf16x8 b0 = *(const bf16x8*)&Ks[nt * 16 + l15][quad * 8];
            bf16x8 b1 = *(const bf16x8*)&Ks[nt * 16 + l15][32 + quad * 8];
            s[nt] = __builtin_amdgcn_mfma_f32_16x16x32_bf16(aQ0, b0, s[nt], 0, 0, 0);
            s[nt] = __builtin_amdgcn_mfma_f32_16x16x32_bf16(aQ1, b1, s[nt], 0, 0, 0);
        }

        // bias + silu/N + diagonal mask -> Ps (packed bf16 conversion)
        const bool diag = (kt == qt);
#pragma unroll
        for (int nt = 0; nt < 4; ++nt) {
            const int m = m0 + nt * 16 + l15;
            const float tk = tkf[nt * 16 + l15];
            float p[4];
#pragma unroll
            for (int reg = 0; reg < 4; ++reg) {
                const float delta = fabsf(tq4[reg] - tk);
                const int bucket = (int)(__log2f(1.0f + delta) * 0.6931471805599453f);
                float val = s[nt][reg] + tw[bucket];
                float pv = silu_over_2048(val);
                if (diag) pv = (m <= nbase + reg) ? pv : 0.0f;
                p[reg] = pv;
            }
            const unsigned int p01 = f2bf2(p[0], p[1]);
            const unsigned int p23 = f2bf2(p[2], p[3]);
            QPs[w * 16 + quad * 4 + 0][nt * 16 + l15] = (unsigned short)p01;
            QPs[w * 16 + quad * 4 + 1][nt * 16 + l15] = (unsigned short)(p01 >> 16);
            QPs[w * 16 + quad * 4 + 2][nt * 16 + l15] = (unsigned short)p23;
            QPs[w * 16 + quad * 4 + 3][nt * 16 + l15] = (unsigned short)(p23 >> 16);
        }
        // wave reads back only its own Ps rows -> no barrier needed

        const bf16x8 aP0 = *(const bf16x8*)&QPs[w * 16 + l15][quad * 8];
        const bf16x8 aP1 = *(const bf16x8*)&QPs[w * 16 + l15][32 + quad * 8];
#pragma unroll
        for (int nt = 0; nt < 4; ++nt) {
            bf16x8 v0 = *(const bf16x8*)&Vt[nt * 16 + l15][quad * 8];
            bf16x8 v1 = *(const bf16x8*)&Vt[nt * 16 + l15][32 + quad * 8];
            oacc[nt] = __builtin_amdgcn_mfma_f32_16x16x32_bf16(aP0, v0, oacc[nt], 0, 0, 0);
            oacc[nt] = __builtin_amdgcn_mfma_f32_16x16x32_bf16(aP1, v1, oacc[nt], 0, 0, 0);
        }
    }

    float* pc = part + (size_t)c * (6400 * 256);
#pragma unroll
    for (int nt = 0; nt < 4; ++nt)
#pragma unroll
        for (int reg = 0; reg < 4; ++reg)
            pc[(off + q0 + w * 16 + quad * 4 + reg) * 256 + hd * 64 + nt * 16 + l15] =
                oacc[nt][reg];
}

// ---------------- K4a: o_in = bf16(u * layernorm(sum_c part[c])) over 256 ----------------
__global__ __launch_bounds__(256) void k4a_ln(const float* __restrict__ part,
                                              const float* __restrict__ u_in,
                                              const int* __restrict__ token_pos,
                                              unsigned short* __restrict__ o_in) {
    const int row = blockIdx.x;
    const int tid = threadIdx.x;
    const int qt = token_pos[row] >> 6;
    const int nch = (qt + 4) >> 2;  // ceil((qt+1)/4), max 8
    float a = 0.0f;
    for (int c = 0; c < nch; ++c) a += part[(size_t)c * (6400 * 256) + row * 256 + tid];
    float s = a, ss = a * a;
#pragma unroll
    for (int off = 32; off > 0; off >>= 1) {
        s += __shfl_down(s, off);
        ss += __shfl_down(ss, off);
    }
    __shared__ float red[8];
    if ((tid & 63) == 0) { red[tid >> 6] = s; red[4 + (tid >> 6)] = ss; }
    __syncthreads();
    s = red[0] + red[1] + red[2] + red[3];
    ss = red[4] + red[5] + red[6] + red[7];
    const float mean = s * (1.0f / 256.0f);
    const float var = ss * (1.0f / 256.0f) - mean * mean;
    const float rstd = rsqrtf(var + 1e-6f);
    const float u = u_in[row * 256 + tid];
    o_in[row * 256 + tid] = f2bf(u * (a - mean) * rstd);
}

// ---------------- K4b: out = o_in @ o_w^T + o_b + x via bf16 MFMA ----------------
__global__ __launch_bounds__(256, 4) void k4b_gemm2(const unsigned short* __restrict__ A,
                                                    const unsigned short* __restrict__ owb,
                                                    const float* __restrict__ ob,
                                                    const float* __restrict__ x,
                                                    float* __restrict__ out) {
    __shared__ __align__(16) unsigned short As[64][72];
    __shared__ __align__(16) unsigned short Bs[64][72];  // [d][k]
    const int tid = threadIdx.x;
    const int lane = tid & 63;
    const int w = tid >> 6;
    const int l15 = lane & 15;
    const int quad = lane >> 4;
    const int bm = blockIdx.y * 64;
    const int bn = blockIdx.x * 64;

    f32x4 acc[4] = {};
    for (int kc = 0; kc < 256; kc += 64) {
        __syncthreads();
#pragma unroll
        for (int i = 0; i < 2; ++i) {
            const int r = (tid >> 3) + i * 32;
            const int c = (tid & 7) * 8;
            *(uint4*)&As[r][c] = *(const uint4*)(A + (bm + r) * 256 + kc + c);
            *(uint4*)&Bs[r][c] = *(const uint4*)(owb + (bn + r) * 256 + kc + c);
        }
        __syncthreads();
        const bf16x8 a0 = *(const bf16x8*)&As[w * 16 + l15][quad * 8];
        const bf16x8 a1 = *(const bf16x8*)&As[w * 16 + l15][32 + quad * 8];
#pragma unroll
        for (int nt = 0; nt < 4; ++nt) {
            bf16x8 b0 = *(const bf16x8*)&Bs[nt * 16 + l15][quad * 8];
            bf16x8 b1 = *(const bf16x8*)&Bs[nt * 16 + l15][32 + quad * 8];
            acc[nt] = __builtin_amdgcn_mfma_f32_16x16x32_bf16(a0, b0, acc[nt], 0, 0, 0);
            acc[nt] = __builtin_amdgcn_mfma_f32_16x16x32_bf16(a1, b1, acc[nt], 0, 0, 0);
        }
    }
    const int m = bm + w * 16 + quad * 4;
#pragma unroll
    for (int nt = 0; nt < 4; ++nt) {
        const int d = bn + nt * 16 + l15;
        const float bias = ob[d];
#pragma unroll
        for (int reg = 0; reg < 4; ++reg)
            out[(m + reg) * 512 + d] = acc[nt][reg] + bias + x[(m + reg) * 512 + d];
    }
}

extern "C" void kernel_launch(void* const* d_in, const int* in_sizes, int n_in,
                              void* d_out, int out_size, void* d_ws, size_t ws_size,
                              hipStream_t stream) {
    const float* x = (const float*)d_in[0];       // [6400,512]
    const float* uvqk = (const float*)d_in[1];    // [512,1024]
    const float* ow = (const float*)d_in[2];      // [512,256]
    const float* ob = (const float*)d_in[3];      // [512]
    const float* tsw = (const float*)d_in[4];     // [129]
    const int* ts = (const int*)d_in[5];          // [4,2048]
    // d_in[6] invalid_attn_mask: pure tril -> implemented as m<=n, not read
    const int* offs = (const int*)d_in[7];        // [5]
    // d_in[8] token_batch (unused)
    const int* token_pos = (const int*)d_in[9];   // [6400]
    float* out = (float*)d_out;                   // [6400,512]

    float* ws = (float*)d_ws;
    float* u = ws;                                // 6400*256 f32
    float* part = u + 6400 * 256;                 // 8*6400*256 f32 (split-K partials)
    unsigned short* xnb = (unsigned short*)(part + 8 * 6400 * 256);  // 6400*512 bf16
    unsigned short* hb = xnb + 6400 * 512;        // 6400*768 bf16 (v cols unwritten)
    unsigned short* o_in = hb + 6400 * 768;       // 6400*256 bf16
    unsigned short* uvqkT = o_in + 6400 * 256;    // 1024*512 bf16
    unsigned short* owb = uvqkT + 1024 * 512;     // 512*256 bf16
    unsigned short* vtb = owb + 512 * 256;        // 256*6400 bf16
    // total ws use: ~86 MB

    k1_ln_prep<<<1792, 256, 0, stream>>>(x, xnb, uvqk, uvqkT, ow, owb);
    k2_gemm1<<<dim3(16, 100), 256, 0, stream>>>(xnb, uvqkT, u, hb, vtb);
    k3_attn<<<dim3(256, 4, 4), 256, 0, stream>>>(hb, vtb, ts, tsw, offs, part);
    k4a_ln<<<6400, 256, 0, stream>>>(part, u, token_pos, o_in);
    k4b_gemm2<<<dim3(8, 100), 256, 0, stream>>>(o_in, owb, ob, x, out);
}